// Round 8
// baseline (411.603 us; speedup 1.0000x reference)
//
#include <hip/hip_runtime.h>
#include <hip/hip_bf16.h>
#include <stdint.h>

#define S_LEN 512
#define BATCH 512
#define HID   128
#define G3    384
#define EMB   50
#define VOC   50000

// sigmoid(x) = rcp(1 + exp2(x * -log2(e))); tanh(y) = 2*sigmoid(2y)-1.
// W_hh/gxv rows are PRE-SCALED: r,z rows by NL2E, n rows by N2L2E.
#define NL2E  (-1.4426950408889634f)
#define N2L2E (-2.8853900817779268f)

typedef __attribute__((ext_vector_type(8))) short short8;
typedef __attribute__((ext_vector_type(4))) float float4v;

__device__ inline unsigned short f2bf(float f) {
  union { float f; uint32_t u; } v; v.f = f;
  uint32_t u = v.u;
  u += 0x7fffu + ((u >> 16) & 1u);   // RNE
  return (unsigned short)(u >> 16);
}
__device__ inline float bitsf(uint32_t u) {
  union { uint32_t u; float f; } v; v.u = u; return v.f;
}
__device__ inline uint32_t fbits(float f) {
  union { float f; uint32_t u; } v; v.f = f; return v.u;
}
__device__ inline float fast_sig(float x) {
  return __builtin_amdgcn_rcpf(1.f + __expf(-x));
}

// ---------------------------------------------------------------------------
// Kernel A0 (tiny): pre-convert W_ih to scaled bf16 B-fragments + biases.
// ---------------------------------------------------------------------------
__global__ __launch_bounds__(128) void prep_wih(
    const float* __restrict__ W_ih, const float* __restrict__ b_ih,
    const float* __restrict__ b_hh, unsigned short* __restrict__ wbf,
    float* __restrict__ sbias) {
  const int nt = blockIdx.x;          // 0..23
  const int kf = threadIdx.x >> 6;    // 0..1
  const int L  = threadIdx.x & 63;
  const int q = L >> 4, ln = L & 15;
  const int g = nt * 16 + ln;
  const float sc = (g < 256) ? NL2E : N2L2E;
  const int k0 = kf * 32 + q * 8;
  short8 v;
#pragma unroll
  for (int i = 0; i < 8; ++i) {
    const int k = k0 + i;
    v[i] = (k < EMB) ? (short)f2bf(W_ih[(size_t)g * EMB + k] * sc) : (short)0;
  }
  *(short8*)(wbf + (size_t)((nt * 2 + kf) * 64 + L) * 8) = v;
  if (threadIdx.x < 16) {
    const int gg = nt * 16 + threadIdx.x;
    const float s2 = (gg < 256) ? NL2E : N2L2E;
    sbias[gg] = s2 * (b_ih[gg] + (gg < 256 ? b_hh[gg] : 0.f));
  }
}

// ---------------------------------------------------------------------------
// Kernel A (MFMA): input-projection table, written as TWO PLANES in the gru
// consumer's exact access pattern:
//   gxrz[v][j] : dword = (r_j lo16, z_j hi16)   (pre-scaled by NL2E)
//   gxn [v][j] : ushort = n_j                    (pre-scaled by N2L2E)
// C staged in LDS in packed layout, bulk-stored coalesced.
// ---------------------------------------------------------------------------
__global__ __launch_bounds__(256) void build_gxv(
    const float* __restrict__ emb, const unsigned short* __restrict__ wbf,
    const float* __restrict__ sbias, uint32_t* __restrict__ gxrz,
    unsigned short* __restrict__ gxn) {
  __shared__ __align__(16) unsigned short crz[64][264]; // (r,z) interleaved, pad
  __shared__ __align__(16) unsigned short cn[64][136];  // n plane, pad
  const int w  = threadIdx.x >> 6;
  const int L  = threadIdx.x & 63;
  const int q  = L >> 4;
  const int ln = L & 15;
  const int vbase = blockIdx.x * 64 + w * 16;
  const int vloc  = w * 16;

  // A fragments: A[m=ln][k=q*8+i] = emb[vbase+ln][k], k zero-padded to 64
  const int vr = min(vbase + ln, VOC - 1);
  const float* arow = emb + (size_t)vr * EMB;
  short8 afr0, afr1;
  {
    float f;
#pragma unroll
    for (int i = 0; i < 8; ++i) {
      const int k = q * 8 + i; f = (k < EMB) ? arow[k] : 0.f;
      afr0[i] = (short)f2bf(f);
    }
#pragma unroll
    for (int i = 0; i < 8; ++i) {
      const int k = 32 + q * 8 + i; f = (k < EMB) ? arow[k] : 0.f;
      afr1[i] = (short)f2bf(f);
    }
  }

#pragma unroll 2
  for (int nt = 0; nt < 24; ++nt) {
    const short8 b0 = *(const short8*)(wbf + (size_t)((nt * 2 + 0) * 64 + L) * 8);
    const short8 b1 = *(const short8*)(wbf + (size_t)((nt * 2 + 1) * 64 + L) * 8);
    const int gg = nt * 16 + ln;
    const float bias = sbias[gg];
    float4v acc = {bias, bias, bias, bias};
    acc = __builtin_amdgcn_mfma_f32_16x16x32_bf16(afr0, b0, acc, 0, 0, 0);
    acc = __builtin_amdgcn_mfma_f32_16x16x32_bf16(afr1, b1, acc, 0, 0, 0);
    // C: col=ln (gate), row=q*4+r (vocab) -> stage into packed planes
    if (nt < 8) {            // r-gate: slot 2j
      const int j = gg;
#pragma unroll
      for (int r = 0; r < 4; ++r) crz[vloc + q * 4 + r][2 * j] = f2bf(acc[r]);
    } else if (nt < 16) {    // z-gate: slot 2j+1
      const int j = gg - 128;
#pragma unroll
      for (int r = 0; r < 4; ++r) crz[vloc + q * 4 + r][2 * j + 1] = f2bf(acc[r]);
    } else {                 // n-gate
      const int j = gg - 256;
#pragma unroll
      for (int r = 0; r < 4; ++r) cn[vloc + q * 4 + r][j] = f2bf(acc[r]);
    }
  }
  __syncthreads();

  // coalesced bulk stores: rz = 64 rows x 32 chunks16B; n = 64 x 16 chunks
  for (int idx = threadIdx.x; idx < 2048; idx += 256) {
    const int row = idx >> 5, c8 = idx & 31;
    const int vrow = blockIdx.x * 64 + row;
    if (vrow < VOC) {
      short8 v = *(const short8*)(&crz[row][c8 * 8]);
      *(short8*)((unsigned short*)gxrz + (size_t)vrow * 256 + c8 * 8) = v;
    }
  }
  for (int idx = threadIdx.x; idx < 1024; idx += 256) {
    const int row = idx >> 4, c8 = idx & 15;
    const int vrow = blockIdx.x * 64 + row;
    if (vrow < VOC) {
      short8 v = *(const short8*)(&cn[row][c8 * 8]);
      *(short8*)(gxn + (size_t)vrow * 128 + c8 * 8) = v;
    }
  }
}

// ---------------------------------------------------------------------------
// Kernel B: persistent GRU recurrence. 256 blocks = 2 GRUs x 128 chunks of
// FOUR batch columns -> 1 block/CU. 8 waves; wave w owns j in [16w,16w+16).
// 12 mfma_f32_16x16x32_bf16 per wave-step; B cols 4..15 broadcast-alias
// cols 0..3 -> C 4x redundant -> per-lane cndmask select (no LDS repack).
// gx loads: ONE dword (r,z packed) + ONE ushort (n) per lane-step from the
// two planes, shared index, depth-2 prefetch, lgkm-only barrier.
// ---------------------------------------------------------------------------
__global__ __launch_bounds__(512) void gru_kernel(
    const int* __restrict__ x1, const int* __restrict__ x2,
    const uint32_t* __restrict__ gxrz, const unsigned short* __restrict__ gxn,
    const float* __restrict__ W_hh, const float* __restrict__ b_hh,
    float* __restrict__ fcin) {
  const int bid   = blockIdx.x;
  const int gru   = bid >> 7;         // 0..1
  const int chunk = bid & 127;        // 0..127
  const int* xs   = gru ? x2 : x1;

  const int tid = threadIdx.x;
  const int w  = tid >> 6;            // wave 0..7
  const int L  = tid & 63;            // lane
  const int q  = L >> 4;              // C-layout quad
  const int ln = L & 15;              // C-layout col group
  const int jb = w * 16;
  const int g3 = ln >> 2;             // which C register this lane consumes
  const int n  = ln & 3;              // batch column (0..3)
  const int j  = jb + q * 4 + g3;     // this lane's hidden unit
  const int ng = chunk * 4 + n;       // global batch index

  __shared__ __align__(16) unsigned short hbuf[2][512]; // h^T packed B-frags

  // --- resident A fragments (pre-scaled): A[m=ln][k=q*8+i] per 16x16x32 ---
  short8 afrag[3][4];
#pragma unroll
  for (int t = 0; t < 3; ++t) {
    const float sc = (t < 2) ? NL2E : N2L2E;
    const float* wr = W_hh + (size_t)(t * 128 + jb + ln) * HID;
#pragma unroll
    for (int kf = 0; kf < 4; ++kf) {
      const int k0 = kf * 32 + q * 8;
      float4v f0 = *(const float4v*)(wr + k0);
      float4v f1 = *(const float4v*)(wr + k0 + 4);
      short8 a;
#pragma unroll
      for (int i = 0; i < 4; ++i) a[i] = (short)f2bf(f0[i] * sc);
#pragma unroll
      for (int i = 0; i < 4; ++i) a[i + 4] = (short)f2bf(f1[i] * sc);
      afrag[t][kf] = a;
    }
  }

  // n-gate C-init: bhn * N2L2E per C row (row r -> j = jb + q*4 + r)
  float4v bhn4;
#pragma unroll
  for (int r = 0; r < 4; ++r) bhn4[r] = N2L2E * b_hh[2 * 128 + jb + q * 4 + r];

  // zero both h buffers (h0 = 0)
  for (int idx = tid; idx < 1024; idx += 512) ((unsigned short*)hbuf)[idx] = 0;

  float h = 0.f;

  // gx prefetch depth 2: one dword (rz) + one ushort (n) per step
  uint32_t rzc, rz1;
  unsigned short nc, n1;
  {
    const size_t i0 = (size_t)xs[ng] * 128 + j;
    rzc = gxrz[i0]; nc = gxn[i0];
    const size_t i1 = (size_t)xs[BATCH + ng] * 128 + j;
    rz1 = gxrz[i1]; n1 = gxn[i1];
  }
  int tokf = xs[2 * BATCH + ng];      // token for s+2

  // h' write offset in packed B-frag order: ((j>>3)*4 + n)*8 + (j&7)
  const int wofs = (((j >> 3) * 4 + n) << 3) + (j & 7);
  // B-frag read offset: cols >=4 alias col&3 (LDS same-address broadcast)
  const int rofs = ((q * 4 + n) << 3);

  const bool selA = (ln & 4) != 0;    // g3 bit 0
  const bool selB = (ln & 8) != 0;    // g3 bit 1

  __syncthreads();

#pragma unroll 2
  for (int s = 0; s < S_LEN; ++s) {
    // issue gx for step s+2 (stays in flight across two lgkm-only barriers)
    const size_t i2 = (size_t)tokf * 128 + j;
    const uint32_t rzf = gxrz[i2];
    const unsigned short nf = gxn[i2];
    const int s3 = (s + 3 < S_LEN) ? (s + 3) : 0;   // uniform clamp
    const int tok3 = xs[s3 * BATCH + ng];

    // B fragments from packed h^T buffer
    const unsigned short* rb = hbuf[s & 1];
    short8 bfrag[4];
#pragma unroll
    for (int kf = 0; kf < 4; ++kf)
      bfrag[kf] = *(const short8*)(rb + kf * 128 + rofs);

    // 2 independent 2-deep MFMA chains per gate; n-gate C-init = scaled bhn
    float vsel[3];
#pragma unroll
    for (int t = 0; t < 3; ++t) {
      float4v a0 = (t == 2) ? bhn4 : (float4v){0.f, 0.f, 0.f, 0.f};
      float4v a1 = {0.f, 0.f, 0.f, 0.f};
      a0 = __builtin_amdgcn_mfma_f32_16x16x32_bf16(afrag[t][0], bfrag[0], a0, 0, 0, 0);
      a1 = __builtin_amdgcn_mfma_f32_16x16x32_bf16(afrag[t][1], bfrag[1], a1, 0, 0, 0);
      a0 = __builtin_amdgcn_mfma_f32_16x16x32_bf16(afrag[t][2], bfrag[2], a0, 0, 0, 0);
      a1 = __builtin_amdgcn_mfma_f32_16x16x32_bf16(afrag[t][3], bfrag[3], a1, 0, 0, 0);
      // per-lane register select: r = g3 (C redundancy across ln-groups)
      const float s0 = selA ? a0[1] : a0[0];
      const float s1 = selA ? a0[3] : a0[2];
      const float u0 = selA ? a1[1] : a1[0];
      const float u1 = selA ? a1[3] : a1[2];
      vsel[t] = (selB ? s1 : s0) + (selB ? u1 : u0);
    }

    // gate math (args pre-scaled): 1 elem/lane; rz unpack is 2 ops
    const float gr = bitsf(rzc << 16) + vsel[0];
    const float gz = bitsf(rzc & 0xffff0000u) + vsel[1];
    const float rg = __builtin_amdgcn_rcpf(1.f + __builtin_amdgcn_exp2f(gr));
    const float zg = __builtin_amdgcn_rcpf(1.f + __builtin_amdgcn_exp2f(gz));
    const float pre = bitsf(((uint32_t)nc) << 16) + rg * vsel[2];
    const float sg  = __builtin_amdgcn_rcpf(1.f + __builtin_amdgcn_exp2f(pre));
    const float nn  = 2.f * sg - 1.f;                // tanh
    h = zg * (h - nn) + nn;

    // write h' as bf16 (round-half-up): one b16 write, all 64 lanes
    hbuf[(s + 1) & 1][wofs] = (unsigned short)((fbits(h) + 0x8000u) >> 16);

    // LDS-only barrier: do NOT drain vmcnt — gx prefetches stay in flight
    asm volatile("s_waitcnt lgkmcnt(0)\n\ts_barrier" ::: "memory");

    rzc = rz1; nc = n1;
    rz1 = rzf; n1 = nf;
    tokf = tok3;
  }

  // final h -> fcin[b][gru*128 + j]
  fcin[(size_t)ng * 256 + gru * 128 + j] = h;
}

// ---------------------------------------------------------------------------
// Kernel C: out[b] = sigmoid(b2 + W2 . relu(b1 + W1 . fcin[b]))
// ---------------------------------------------------------------------------
__global__ __launch_bounds__(128) void head_kernel(
    const float* __restrict__ fcin, const float* __restrict__ W1,
    const float* __restrict__ b1, const float* __restrict__ W2,
    const float* __restrict__ b2, float* __restrict__ out) {
  __shared__ float fc[256];
  __shared__ float part[2];
  const int b = blockIdx.x, t = threadIdx.x;
  fc[t]       = fcin[(size_t)b * 256 + t];
  fc[t + 128] = fcin[(size_t)b * 256 + t + 128];
  __syncthreads();

  float acc = b1[t];
#pragma unroll 8
  for (int k = 0; k < 256; ++k) acc += W1[t * 256 + k] * fc[k];
  const float hid = fmaxf(acc, 0.f);

  float v = hid * W2[t];
#pragma unroll
  for (int o = 32; o > 0; o >>= 1) v += __shfl_xor(v, o, 64);
  if ((t & 63) == 0) part[t >> 6] = v;
  __syncthreads();
  if (t == 0) {
    const float s = part[0] + part[1] + b2[0];
    out[b] = fast_sig(s);
  }
}

// ---------------------------------------------------------------------------
extern "C" void kernel_launch(void* const* d_in, const int* in_sizes, int n_in,
                              void* d_out, int out_size, void* d_ws, size_t ws_size,
                              hipStream_t stream) {
  const int*   x1   = (const int*)d_in[0];
  const int*   x2   = (const int*)d_in[1];
  const float* emb  = (const float*)d_in[2];
  const float* W_ih = (const float*)d_in[3];
  const float* W_hh = (const float*)d_in[4];
  const float* b_ih = (const float*)d_in[5];
  const float* b_hh = (const float*)d_in[6];
  const float* W1   = (const float*)d_in[7];
  const float* b1   = (const float*)d_in[8];
  const float* W2   = (const float*)d_in[9];
  const float* b2   = (const float*)d_in[10];
  float* out = (float*)d_out;

  char* ws = (char*)d_ws;
  uint32_t*       gxrz = (uint32_t*)ws;                           // 25.6 MB
  unsigned short* gxn  = (unsigned short*)(ws + 25600000);        // 12.8 MB
  float*          fcin = (float*)(ws + 38400000);                 // 512 KB
  unsigned short* wbf  = (unsigned short*)(ws + 38924288);        // 48 KB
  float*          sbias= (float*)(ws + 38973440);                 // 1.5 KB

  prep_wih<<<24, 128, 0, stream>>>(W_ih, b_ih, b_hh, wbf, sbias);
  build_gxv<<<(VOC + 63) / 64, 256, 0, stream>>>(emb, wbf, sbias, gxrz, gxn);
  gru_kernel<<<256, 512, 0, stream>>>(x1, x2, gxrz, gxn, W_hh, b_hh, fcin);
  head_kernel<<<512, 128, 0, stream>>>(fcin, W1, b1, W2, b2, out);
}